// Round 2
// baseline (131.190 us; speedup 1.0000x reference)
//
#include <hip/hip_runtime.h>
#include <hip/hip_cooperative_groups.h>
#include <math.h>

namespace cg = cooperative_groups;

#define NN 8192
#define HH 128
#define LRELU_ALPHA 0.2f
#define R_ROWS 152          // rows with t_i possibly nonzero in f32 (i >= 8040)
#define I0 (NN - R_ROWS)
#define NBLK 256
#define NTHR 512

// Workspace layout (floats):
//   f1    [NN]
//   f2    [NN]
//   wrow  [R_ROWS * NN]
//   vpart [128 * HH]

__global__ __launch_bounds__(NTHR) void k_gat_fused(const float* __restrict__ inp,
                                                    const int* __restrict__ A,
                                                    const float* __restrict__ W,
                                                    const float* __restrict__ a,
                                                    float* __restrict__ ws,
                                                    float* __restrict__ out) {
    cg::grid_group grid = cg::this_grid();

    float* f1    = ws;
    float* f2    = ws + NN;
    float* wrow  = ws + 2 * NN;
    float* vpart = ws + 2 * NN + (size_t)R_ROWS * NN;

    __shared__ float s[NN];          // 32 KB scratch (s-row in P2, reductions in P3/P4)
    __shared__ float u1s[HH], u2s[HH];
    __shared__ float mred[8], zred[8];

    const int tid  = threadIdx.x;
    const int wave = tid >> 6;
    const int lane = tid & 63;
    const int bid  = blockIdx.x;

    // ---------------- P0: u1 = W@a1, u2 = W@a2 (redundant per block, into LDS) ----
    {
        float2 av1 = ((const float2*)a)[lane];
        float2 av2 = ((const float2*)(a + HH))[lane];
        for (int k = wave; k < HH; k += 8) {
            float2 x = ((const float2*)(W + (size_t)k * HH))[lane];
            float p1 = x.x * av1.x + x.y * av1.y;
            float p2 = x.x * av2.x + x.y * av2.y;
            for (int off = 32; off; off >>= 1) {
                p1 += __shfl_down(p1, off);
                p2 += __shfl_down(p2, off);
            }
            if (lane == 0) { u1s[k] = p1; u2s[k] = p2; }
        }
    }
    __syncthreads();

    // ---------------- P1: f1 = inp@u1, f2 = inp@u2 (32 rows per block) -----------
    {
        float2 uv1 = ((const float2*)u1s)[lane];
        float2 uv2 = ((const float2*)u2s)[lane];
        int r0 = bid * (NN / NBLK);
        for (int rr = wave; rr < NN / NBLK; rr += 8) {
            int r = r0 + rr;
            float2 x = ((const float2*)(inp + (size_t)r * HH))[lane];
            float p1 = x.x * uv1.x + x.y * uv1.y;
            float p2 = x.x * uv2.x + x.y * uv2.y;
            for (int off = 32; off; off >>= 1) {
                p1 += __shfl_down(p1, off);
                p2 += __shfl_down(p2, off);
            }
            if (lane == 0) { f1[r] = p1; f2[r] = p2; }
        }
    }
    grid.sync();

    // ---------------- P2: per-row softmax -> wrow[ii][j] = (t_i/Z_i) exp(s-m) ----
    if (bid < R_ROWS) {
        int i = I0 + bid;
        float f1i = f1[i];
        const int* arow = A + (size_t)i * NN;
        for (int jt = tid; jt < NN; jt += NTHR) {
            int av = arow[jt];
            float s0 = f1i + f2[jt];
            float sv = s0 > 0.f ? s0 : LRELU_ALPHA * s0;
            s[jt] = ((av > 0) || (jt == i)) ? sv : -INFINITY;
        }
        __syncthreads();
        // block max
        float m = -INFINITY;
        for (int jt = tid; jt < NN; jt += NTHR) m = fmaxf(m, s[jt]);
        for (int off = 32; off; off >>= 1) m = fmaxf(m, __shfl_xor(m, off));
        if (lane == 0) mred[wave] = m;
        __syncthreads();
        float mm = mred[0];
        #pragma unroll
        for (int w = 1; w < 8; w++) mm = fmaxf(mm, mred[w]);
        // exp + block sum (overwrite s with exp values)
        float z = 0.f;
        for (int jt = tid; jt < NN; jt += NTHR) {
            float e = __expf(s[jt] - mm);
            s[jt] = e;
            z += e;
        }
        for (int off = 32; off; off >>= 1) z += __shfl_xor(z, off);
        if (lane == 0) zred[wave] = z;
        __syncthreads();
        float zz = zred[0];
        #pragma unroll
        for (int w = 1; w < 8; w++) zz += zred[w];
        float ci = exp2f((float)(i - NN)) / zz;   // t_i (normalized) / Z_i
        for (int jt = tid; jt < NN; jt += NTHR)
            wrow[(size_t)bid * NN + jt] = ci * s[jt];
    }
    grid.sync();

    // ---------------- P3: w_j = sum_ii wrow[ii][j]; vpart[b] = sum_j w_j inp[j] --
    if (bid < 128) {
        int jbase = bid * 64;
        float wacc = 0.f;
        for (int ii = wave; ii < R_ROWS; ii += 8)
            wacc += wrow[(size_t)ii * NN + jbase + lane];
        s[wave * 64 + lane] = wacc;
        __syncthreads();
        float* wj = s + 512;
        if (tid < 64) {
            float wv = 0.f;
            #pragma unroll
            for (int w = 0; w < 8; w++) wv += s[w * 64 + tid];
            wj[tid] = wv;
        }
        __syncthreads();
        int k = tid & 127, q = tid >> 7;
        float acc = 0.f;
        for (int jj = q; jj < 64; jj += 4)
            acc += wj[jj] * inp[(size_t)(jbase + jj) * HH + k];
        float* vred = s + 1024;
        vred[q * 128 + k] = acc;
        __syncthreads();
        if (tid < 128)
            vpart[(size_t)bid * HH + tid] =
                vred[tid] + vred[128 + tid] + vred[256 + tid] + vred[384 + tid];
    }
    grid.sync();

    // ---------------- P4: v = sum(vpart); h_t = v@W; out = elu(h_t) --------------
    if (bid == 0) {
        int k = tid & 127, q = tid >> 7;
        float acc = 0.f;
        for (int b = q; b < 128; b += 4) acc += vpart[(size_t)b * HH + k];
        s[q * 128 + k] = acc;
        __syncthreads();
        float* vsh = s + 512;
        if (tid < 128) vsh[tid] = s[tid] + s[128 + tid] + s[256 + tid] + s[384 + tid];
        __syncthreads();
        float h = 0.f;
        for (int kk = q; kk < 128; kk += 4) h += vsh[kk] * W[(size_t)kk * HH + k];
        s[1024 + q * 128 + k] = h;
        __syncthreads();
        if (tid < 128) {
            float ht = s[1024 + tid] + s[1024 + 128 + tid] +
                       s[1024 + 256 + tid] + s[1024 + 384 + tid];
            out[tid] = ht > 0.f ? ht : expm1f(ht);
        }
    }
}

extern "C" void kernel_launch(void* const* d_in, const int* in_sizes, int n_in,
                              void* d_out, int out_size, void* d_ws, size_t ws_size,
                              hipStream_t stream) {
    const float* inp = (const float*)d_in[0];   // [8192,128] f32
    const int*   A   = (const int*)d_in[1];     // [8192,8192] i32
    const float* W   = (const float*)d_in[2];   // [128,128] f32
    const float* a   = (const float*)d_in[3];   // [256,1] f32
    float* out = (float*)d_out;                 // [128] f32
    float* ws  = (float*)d_ws;

    void* kargs[] = {(void*)&inp, (void*)&A, (void*)&W, (void*)&a,
                     (void*)&ws, (void*)&out};
    hipLaunchCooperativeKernel((const void*)k_gat_fused, dim3(NBLK), dim3(NTHR),
                               kargs, 0, stream);
}

// Round 3
// 53.658 us; speedup vs baseline: 2.4449x; 2.4449x over previous
//
#include <hip/hip_runtime.h>
#include <math.h>

#define NN 8192
#define HH 128
#define LRELU_ALPHA 0.2f
#define R_ROWS 152          // rows with t_i possibly nonzero in f32 (i >= 8043), padded
#define I0 (NN - R_ROWS)    // 8040

// ---------- K1: u1 = W @ a[:H], u2 = W @ a[H:]  (each [H]) ----------
__global__ __launch_bounds__(256) void k_prep(const float* __restrict__ W,
                                              const float* __restrict__ a,
                                              float* __restrict__ u1,
                                              float* __restrict__ u2) {
    int wave = threadIdx.x >> 6, lane = threadIdx.x & 63;
    float2 av1 = ((const float2*)a)[lane];
    float2 av2 = ((const float2*)(a + HH))[lane];
    for (int k = wave; k < HH; k += 4) {
        float2 x = ((const float2*)(W + (size_t)k * HH))[lane];
        float p1 = x.x * av1.x + x.y * av1.y;
        float p2 = x.x * av2.x + x.y * av2.y;
        for (int off = 32; off; off >>= 1) {
            p1 += __shfl_down(p1, off);
            p2 += __shfl_down(p2, off);
        }
        if (lane == 0) { u1[k] = p1; u2[k] = p2; }
    }
}

// ---------- K2: f1 = inp @ u1, f2 = inp @ u2  (each [N]) ----------
__global__ __launch_bounds__(256) void k_f(const float* __restrict__ inp,
                                           const float* __restrict__ u1,
                                           const float* __restrict__ u2,
                                           float* __restrict__ f1,
                                           float* __restrict__ f2) {
    int wave = threadIdx.x >> 6, lane = threadIdx.x & 63;
    int r = blockIdx.x * 4 + wave;
    float2 x   = ((const float2*)(inp + (size_t)r * HH))[lane];
    float2 av1 = ((const float2*)u1)[lane];
    float2 av2 = ((const float2*)u2)[lane];
    float p1 = x.x * av1.x + x.y * av1.y;
    float p2 = x.x * av2.x + x.y * av2.y;
    for (int off = 32; off; off >>= 1) {
        p1 += __shfl_down(p1, off);
        p2 += __shfl_down(p2, off);
    }
    if (lane == 0) { f1[r] = p1; f2[r] = p2; }
}

// ---------- K3: per-row softmax, one A pass; wrow[ii][j] = (t_i/Z_i) exp(s-m) ----
__global__ __launch_bounds__(512) void k_row(const int* __restrict__ A,
                                             const float* __restrict__ f1,
                                             const float* __restrict__ f2,
                                             float* __restrict__ wrow) {
    const int ii = blockIdx.x;
    const int i  = I0 + ii;
    const int tid = threadIdx.x, wave = tid >> 6, lane = tid & 63;

    __shared__ float s[NN];        // 32 KB staged scores
    __shared__ float red[8];

    const int4*   arow = (const int4*)(A + (size_t)i * NN);
    const float4* f2v  = (const float4*)f2;
    const float f1i = f1[i];

    // pass 1: read A row once (int4), compute masked scores into LDS, track max
    float m = -INFINITY;
    for (int t = tid; t < NN / 4; t += 512) {
        int4   av = arow[t];
        float4 fv = f2v[t];
        int j0 = 4 * t;
        float4 sv;
        float x;
        x = f1i + fv.x; x = x > 0.f ? x : LRELU_ALPHA * x;
        sv.x = ((av.x > 0) || (j0 + 0 == i)) ? x : -INFINITY;
        x = f1i + fv.y; x = x > 0.f ? x : LRELU_ALPHA * x;
        sv.y = ((av.y > 0) || (j0 + 1 == i)) ? x : -INFINITY;
        x = f1i + fv.z; x = x > 0.f ? x : LRELU_ALPHA * x;
        sv.z = ((av.z > 0) || (j0 + 2 == i)) ? x : -INFINITY;
        x = f1i + fv.w; x = x > 0.f ? x : LRELU_ALPHA * x;
        sv.w = ((av.w > 0) || (j0 + 3 == i)) ? x : -INFINITY;
        ((float4*)s)[t] = sv;
        m = fmaxf(m, fmaxf(fmaxf(sv.x, sv.y), fmaxf(sv.z, sv.w)));
    }
    for (int off = 32; off; off >>= 1) m = fmaxf(m, __shfl_xor(m, off));
    if (lane == 0) red[wave] = m;
    __syncthreads();
    float mm = red[0];
    #pragma unroll
    for (int w = 1; w < 8; w++) mm = fmaxf(mm, red[w]);
    __syncthreads();

    // pass 2: exp from LDS, sum
    float z = 0.f;
    for (int t = tid; t < NN / 4; t += 512) {
        float4 sv = ((float4*)s)[t];
        sv.x = __expf(sv.x - mm);
        sv.y = __expf(sv.y - mm);
        sv.z = __expf(sv.z - mm);
        sv.w = __expf(sv.w - mm);
        ((float4*)s)[t] = sv;
        z += sv.x + sv.y + sv.z + sv.w;
    }
    for (int off = 32; off; off >>= 1) z += __shfl_xor(z, off);
    if (lane == 0) red[wave] = z;
    __syncthreads();
    float zz = red[0];
    #pragma unroll
    for (int w = 1; w < 8; w++) zz += red[w];

    // pass 3: scale and write
    float ci = exp2f((float)(i - NN)) / zz;   // normalized t_i / Z_i
    float4* wout = (float4*)(wrow + (size_t)ii * NN);
    for (int t = tid; t < NN / 4; t += 512) {
        float4 ev = ((float4*)s)[t];
        ev.x *= ci; ev.y *= ci; ev.z *= ci; ev.w *= ci;
        wout[t] = ev;
    }
}

// ---------- K4: w_j = sum_ii wrow[ii][j]; vpart[b][k] = sum_j w_j inp[j][k] ----
__global__ __launch_bounds__(256) void k_v(const float* __restrict__ inp,
                                           const float* __restrict__ wrow,
                                           float* __restrict__ vpart) {
    const int b = blockIdx.x;        // 128 blocks, 64 j's each
    const int jbase = b * 64;
    const int tid = threadIdx.x;
    __shared__ float red[256];
    __shared__ float wj[64];

    // step 1: w_j for this block's 64 columns (4 groups over 152 rows)
    int jj = tid & 63, grp = tid >> 6;
    float acc = 0.f;
    for (int ii = grp; ii < R_ROWS; ii += 4)
        acc += wrow[(size_t)ii * NN + jbase + jj];
    red[tid] = acc;
    __syncthreads();
    if (tid < 64) wj[tid] = red[tid] + red[64 + tid] + red[128 + tid] + red[192 + tid];
    __syncthreads();

    // step 2: weighted sum of inp rows
    int k = tid & 127, half = tid >> 7;
    float v = 0.f;
    for (int j2 = half; j2 < 64; j2 += 2)
        v += wj[j2] * inp[(size_t)(jbase + j2) * HH + k];
    red[tid] = v;
    __syncthreads();
    if (half == 0) vpart[(size_t)b * HH + k] = red[k] + red[128 + k];
}

// ---------- K5: v = sum(vpart); h_t = v @ W; out = elu(h_t) ----------
__global__ __launch_bounds__(512) void k_final(const float* __restrict__ W,
                                               const float* __restrict__ vpart,
                                               float* __restrict__ out) {
    __shared__ float red[512];
    __shared__ float v[128];
    int tid = threadIdx.x, k = tid & 127, q = tid >> 7;
    float acc = 0.f;
    for (int b = q; b < 128; b += 4) acc += vpart[(size_t)b * HH + k];
    red[q * 128 + k] = acc;
    __syncthreads();
    if (tid < 128) v[tid] = red[tid] + red[128 + tid] + red[256 + tid] + red[384 + tid];
    __syncthreads();
    float h = 0.f;
    for (int kk = q; kk < 128; kk += 4) h += v[kk] * W[(size_t)kk * HH + k];
    red[q * 128 + k] = h;
    __syncthreads();
    if (tid < 128) {
        float ht = red[tid] + red[128 + tid] + red[256 + tid] + red[384 + tid];
        out[tid] = ht > 0.f ? ht : expm1f(ht);
    }
}

extern "C" void kernel_launch(void* const* d_in, const int* in_sizes, int n_in,
                              void* d_out, int out_size, void* d_ws, size_t ws_size,
                              hipStream_t stream) {
    const float* inp = (const float*)d_in[0];   // [8192,128] f32
    const int*   A   = (const int*)d_in[1];     // [8192,8192] i32
    const float* W   = (const float*)d_in[2];   // [128,128] f32
    const float* a   = (const float*)d_in[3];   // [256,1] f32
    float* out = (float*)d_out;                 // [128] f32
    float* ws  = (float*)d_ws;

    // workspace layout (floats)
    float* u1    = ws;                            // 128
    float* u2    = ws + 128;                      // 128
    float* f1    = ws + 256;                      // 8192
    float* f2    = ws + 256 + NN;                 // 8192
    float* wrow  = ws + 256 + 2 * NN;             // 152*8192 = 1245184
    float* vpart = wrow + (size_t)R_ROWS * NN;    // 128*128

    k_prep <<<1,       256, 0, stream>>>(W, a, u1, u2);
    k_f    <<<NN / 4,  256, 0, stream>>>(inp, u1, u2, f1, f2);
    k_row  <<<R_ROWS,  512, 0, stream>>>(A, f1, f2, wrow);
    k_v    <<<128,     256, 0, stream>>>(inp, wrow, vpart);
    k_final<<<1,       512, 0, stream>>>(W, vpart, out);
}